// Round 8
// baseline (374.039 us; speedup 1.0000x reference)
//
#include <hip/hip_runtime.h>
#include <stdint.h>

// Problem constants
#define BB 16
#define T1C 512
#define T2C 64
#define DC 768
#define HC 12
#define EC 64
#define SC 576          // T1+T2
#define QSCALE 0.35355339059327379f   // 64^-0.25

typedef __attribute__((ext_vector_type(8))) short bf16x8;   // 8 bf16 = 4 VGPRs
typedef __attribute__((ext_vector_type(4))) float f32x4;    // MFMA C/D

// ---------- bf16 helpers ----------
__device__ __forceinline__ uint16_t f2b(float f) {          // RNE
    union { float f; uint32_t i; } v; v.f = f;
    return (uint16_t)((v.i + 0x7fffu + ((v.i >> 16) & 1u)) >> 16);
}
__device__ __forceinline__ uint16_t f2bfast(float f) {      // round-half-up (cheap)
    union { float f; uint32_t i; } v; v.f = f;
    return (uint16_t)((v.i + 0x8000u) >> 16);
}
__device__ __forceinline__ uint32_t pk2(float a, float b) {
    return (uint32_t)f2b(a) | ((uint32_t)f2b(b) << 16);
}

// async global->LDS, 16B per lane; LDS dest = wave-uniform base + lane*16
__device__ __forceinline__ void gll16(const void* g, void* l) {
    __builtin_amdgcn_global_load_lds(
        (const __attribute__((address_space(1))) uint32_t*)(uintptr_t)g,
        (__attribute__((address_space(3))) uint32_t*)(uintptr_t)l, 16, 0, 0);
}

#define WT_BLOCKS (24 * 24 * 14)   // 8064 wtrans blocks
#define XS_BLOCKS 3456             // 884736 chunks / 256

// ---------- fused prep: wtrans + xswz + detect in ONE launch ----------
// wtrans emits Wt[z] in CHUNK order (same frag layout as Xs):
//   chunk cc = ((p*24 + kt)*4 + qd)*16 + rlid, p = f>>4, rlid = f&15,
//   holding W_z[kt*32+qd*8 .. +7][p*16+rlid].
__global__ __launch_bounds__(256) void prep(
    const float* __restrict__ Wf, const float* __restrict__ Wi,
    const float* __restrict__ Wuv, const float* __restrict__ Wul,
    uint16_t* __restrict__ Wt,
    const float* __restrict__ Xf, const float* __restrict__ Xi,
    uint16_t* __restrict__ Of, uint16_t* __restrict__ Oi,
    const uint32_t* __restrict__ mw, int* __restrict__ flags)
{
    __shared__ union { float tile[32][33]; int d[3]; } sh;
    const int bid = blockIdx.x;
    if (bid < WT_BLOCKS) {
        // ---- weight transpose + f32->bf16 -> chunk-order Wt ----
        const int z = bid / 576, r = bid % 576;
        const int kx = r % 24, fy = r / 24;      // k-tile kt = kx, f block = fy*32
        const float* src = (z < 6)  ? Wf + (size_t)z * DC * DC
                         : (z < 12) ? Wi + (size_t)(z - 6) * DC * DC
                         : (z == 12 ? Wuv : Wul);
        uint16_t* dst = Wt + (size_t)z * DC * DC;
        const int tx = threadIdx.x & 31, ty = threadIdx.x >> 5;
        const int k0 = kx * 32, f0 = fy * 32;
#pragma unroll
        for (int q = 0; q < 4; q++)
            sh.tile[ty + q * 8][tx] = src[(size_t)(k0 + ty + q * 8) * DC + f0 + tx];
        __syncthreads();
        if (threadIdx.x < 128) {
            const int fl = threadIdx.x & 31, kg = threadIdx.x >> 5;  // f lane, qd
            const int p = (f0 + fl) >> 4, rlid = fl & 15;
            uint4 o;
            o.x = pk2(sh.tile[kg * 8 + 0][fl], sh.tile[kg * 8 + 1][fl]);
            o.y = pk2(sh.tile[kg * 8 + 2][fl], sh.tile[kg * 8 + 3][fl]);
            o.z = pk2(sh.tile[kg * 8 + 4][fl], sh.tile[kg * 8 + 5][fl]);
            o.w = pk2(sh.tile[kg * 8 + 6][fl], sh.tile[kg * 8 + 7][fl]);
            *(uint4*)(dst + ((size_t)((p * 24 + kx) * 4 + kg) * 16 + rlid) * 8) = o;
        }
    } else if (bid < WT_BLOCKS + XS_BLOCKS) {
        // ---- X f32 -> bf16 swizzle (MFMA A-fragment order) ----
        const int nf = BB * T1C * DC / 8;
        const int ni = BB * T2C * DC / 8;
        int t = (bid - WT_BLOCKS) * 256 + threadIdx.x;
        const float* src; uint16_t* dst; int cc;
        if (t < nf) { src = Xf; dst = Of; cc = t; }
        else        { cc = t - nf; if (cc >= ni) return; src = Xi; dst = Oi; }
        int rlid = cc & 15;
        int t2 = cc >> 4;
        int qd = t2 & 3;
        int t3 = t2 >> 2;
        int kt = t3 % 24;
        int p  = t3 / 24;
        const float* sp = src + (size_t)(p * 16 + rlid) * DC + kt * 32 + qd * 8;
        float4 a = *(const float4*)sp;
        float4 b = *(const float4*)(sp + 4);
        uint4 o;
        o.x = pk2(a.x, a.y); o.y = pk2(a.z, a.w);
        o.z = pk2(b.x, b.y); o.w = pk2(b.z, b.w);
        *(uint4*)(dst + (size_t)cc * 8) = o;
    } else {
        // ---- mask layout detect (deterministic -> graph-safe) ----
        if (threadIdx.x == 0) { sh.d[0] = 0; sh.d[1] = 0; sh.d[2] = 0; }
        __syncthreads();
        int lW = 0, lB = 0, lL = 0;
        for (int i = threadIdx.x; i < 2304; i += 256) {
            uint32_t w = mw[i];
            if (w > 1u) lW = 1;
            if (((w) & 0xffu) > 1u || ((w >> 8) & 0xffu) > 1u ||
                ((w >> 16) & 0xffu) > 1u || ((w >> 24) & 0xffu) > 1u) lB = 1;
            if ((w & 0xffffu) > 1u) lL = 1;
        }
        if (lW) atomicOr(&sh.d[0], 1);
        if (lB) atomicOr(&sh.d[1], 1);
        if (lL) atomicOr(&sh.d[2], 1);
        __syncthreads();
        if (threadIdx.x == 0)
            flags[0] = (!sh.d[0]) ? 0 : ((!sh.d[1]) ? 1 : (sh.d[2] ? 2 : 0));
    }
}

#define BSTR 76   // epilogue bounce stride (bf16 elems), conflict-free

// ---------- MFMA projection GEMM: 128x256 block, 64x128 wave tiles ----------
// 4 waves (2m x 2n), BK=32, chunk-order A+B double-buffered LDS (48 KB),
// counted vmcnt(6). Bigger wave tile cuts LDS read bytes/FLOP 25% (12 KB per
// 524 KFLOP vs 8 KB per 262) and halves barriers per FLOP -- the LDS read
// pipe was the top-utilization resource at R7's 64x64 tile.
__global__ __launch_bounds__(256, 3) void gemm_proj_mfma(
    const uint16_t* __restrict__ Xsf, const uint16_t* __restrict__ Xsi,
    const uint16_t* __restrict__ Wt,
    const float* __restrict__ b_f, const float* __restrict__ b_i,
    uint16_t* __restrict__ Pf, uint16_t* __restrict__ Pi)
{
    __shared__ union {
        struct { uint16_t A[2][128 * 32]; uint16_t B[2][256 * 32]; } st; // 48 KB
        uint16_t bounce[4][16 * BSTR];        // 9.5 KB epilogue
    } sm;
    const int tid = threadIdx.x;
    const int w = tid >> 6, l = tid & 63;
    const bool isf = (blockIdx.x < 64);
    const int mx = isf ? blockIdx.x : blockIdx.x - 64;
    const int m0 = mx * 128;
    const int T  = isf ? T1C : T2C;
    const uint16_t* Xs = isf ? Xsf : Xsi;
    const float* bias  = isf ? b_f : b_i;
    uint16_t* P        = isf ? Pf : Pi;
    const int vmask    = isf ? 0x24 : 0x22;
    const int k6 = blockIdx.y / 3, nb = blockIdx.y % 3;
    const int n0 = nb * 256;
    const uint16_t* Bsrc = Wt + (size_t)((isf ? 0 : 6) + k6) * DC * DC;

    const int lid = l & 15, qd = l >> 4;
    const int wm = w >> 1, wn = w & 1;

    f32x4 acc[4][8] = {};

    // stage tile t: A panels mx*8 + w*2+{0,1}; B panels nb*16 + w*4+{0..3}
#define PJ_S(bu, t) { \
        _Pragma("unroll") for (int n = 0; n < 2; n++) \
            gll16(Xs + ((size_t)((mx * 8 + w * 2 + n) * 24 + (t)) * 64 + l) * 8, \
                  &sm.st.A[bu][(w * 2 + n) * 512]); \
        _Pragma("unroll") for (int n = 0; n < 4; n++) \
            gll16(Bsrc + ((size_t)((nb * 16 + w * 4 + n) * 24 + (t)) * 64 + l) * 8, \
                  &sm.st.B[bu][(w * 4 + n) * 512]); }
#define PJ_C(bu) { bf16x8 aq[4], bq[8]; \
        _Pragma("unroll") for (int i = 0; i < 4; i++) \
            aq[i] = *(const bf16x8*)&sm.st.A[bu][((wm * 4 + i) * 64 + l) * 8]; \
        _Pragma("unroll") for (int j = 0; j < 8; j++) \
            bq[j] = *(const bf16x8*)&sm.st.B[bu][((wn * 8 + j) * 64 + l) * 8]; \
        _Pragma("unroll") for (int i = 0; i < 4; i++) \
        _Pragma("unroll") for (int j = 0; j < 8; j++) \
            acc[i][j] = __builtin_amdgcn_mfma_f32_16x16x32_bf16(aq[i], bq[j], acc[i][j], 0, 0, 0); }

    PJ_S(0, 0);                                // prologue: tile 0 in flight (6)

    for (int kt = 0; kt < DC / 32; ++kt) {
        const int cb = kt & 1, nx = cb ^ 1;
        __builtin_amdgcn_s_barrier();          // all waves done reading buf nx
        __builtin_amdgcn_sched_barrier(0);
        if (kt < 23) {
            PJ_S(nx, kt + 1);                  // outstanding: S(t)6 + S(t+1)6
            asm volatile("s_waitcnt vmcnt(6)" ::: "memory");  // retire S(t)
        } else {
            asm volatile("s_waitcnt vmcnt(0)" ::: "memory");  // final drain
        }
        __builtin_amdgcn_sched_barrier(0);
        __builtin_amdgcn_s_barrier();          // publish tile kt cross-wave
        __builtin_amdgcn_sched_barrier(0);
        PJ_C(cb);
    }
#undef PJ_S
#undef PJ_C

    float bv[8];
#pragma unroll
    for (int j = 0; j < 8; j++)
        bv[j] = bias[k6 * DC + n0 + wn * 128 + j * 16 + lid];
    __syncthreads();   // all waves' K-loop LDS reads done before bounce overwrite

    uint16_t* reg = sm.bounce[w];
    const int mb = m0 + wm * 64;
    const int b = mb / T, tb = mb - b * T;     // 64-row wave tile never crosses b
    const int rrow = l >> 2;                   // readback row within pass
    const int rcol = (l & 3) * 16;             // readback col chunk

    if (!((vmask >> k6) & 1)) {
        // normal [t][e]: per head hl, pass p = m-rows p*16..+15 (i = p)
#pragma unroll
        for (int hl = 0; hl < 2; hl++) {
            const int h = nb * 4 + wn * 2 + hl;
            uint16_t* dst0 = P + ((((size_t)k6 * BB + b) * HC + h) * T + tb + rrow) * EC + rcol;
#pragma unroll
            for (int p = 0; p < 4; p++) {
#pragma unroll
                for (int jj = 0; jj < 4; jj++)
#pragma unroll
                    for (int r = 0; r < 4; r++)
                        reg[(qd * 4 + r) * BSTR + jj * 16 + lid] =
                            f2b((acc[p][hl * 4 + jj][r] + bv[hl * 4 + jj]) * QSCALE);
                uint4 d0 = *(const uint4*)&reg[rrow * BSTR + rcol];
                uint4 d1 = *(const uint4*)&reg[rrow * BSTR + rcol + 8];
                uint16_t* dst = dst0 + (size_t)p * 16 * EC;
                *(uint4*)dst = d0;
                *(uint4*)(dst + 8) = d1;
            }
        }
    } else {
        // transposed [e][t]: per head hl, pass p = e-rows p*16..+15 (j = hl*4+p)
#pragma unroll
        for (int hl = 0; hl < 2; hl++) {
            const int h = nb * 4 + wn * 2 + hl;
            uint16_t* dst0 = P + (size_t)k6 * BB * HC * T * EC
                               + (((size_t)b * HC + h) * EC + rrow) * T + tb + rcol;
#pragma unroll
            for (int p = 0; p < 4; p++) {
#pragma unroll
                for (int i = 0; i < 4; i++) {
                    uint32_t w0 = pk2((acc[i][hl * 4 + p][0] + bv[hl * 4 + p]) * QSCALE,
                                      (acc[i][hl * 4 + p][1] + bv[hl * 4 + p]) * QSCALE);
                    uint32_t w1 = pk2((acc[i][hl * 4 + p][2] + bv[hl * 4 + p]) * QSCALE,
                                      (acc[i][hl * 4 + p][3] + bv[hl * 4 + p]) * QSCALE);
                    *(uint2*)&reg[lid * BSTR + i * 16 + qd * 4] = make_uint2(w0, w1);
                }
                uint4 d0 = *(const uint4*)&reg[rrow * BSTR + rcol];
                uint4 d1 = *(const uint4*)&reg[rrow * BSTR + rcol + 8];
                uint16_t* dst = dst0 + (size_t)p * 16 * T;
                *(uint4*)dst = d0;
                *(uint4*)(dst + 8) = d1;
            }
        }
    }
}

// ---------- MFMA output GEMM: R6 chunk-order both-staged schedule ----------
__global__ __launch_bounds__(256, 4) void gemm_out_mfma(
    const uint16_t* __restrict__ Osv, const uint16_t* __restrict__ Osl,
    const uint16_t* __restrict__ Wt,
    const float* __restrict__ bu_v, const float* __restrict__ bu_l,
    float* __restrict__ out)
{
    __shared__ struct { uint16_t A[2][128 * 32]; uint16_t B[2][128 * 32]; } st;
    const int tid = threadIdx.x;
    const int w = tid >> 6, l = tid & 63;
    const bool isv = (blockIdx.x < 64);
    const int mx = isv ? blockIdx.x : blockIdx.x - 64;
    const int m0 = mx * 128;
    const int rowoff = isv ? 0 : BB * T1C;
    const uint16_t* A = isv ? Osv : Osl;
    const uint16_t* Wtm = Wt + (size_t)(isv ? 12 : 13) * DC * DC;
    const float* bias = isv ? bu_v : bu_l;
    const int n0 = blockIdx.y * 128;
    const int lid = l & 15, qd = l >> 4;
    const int wm = w >> 1, wn = w & 1;
    const int c0 = w * 2;

    f32x4 acc[4][4] = {};

#define GO_S(bu, t) { \
        _Pragma("unroll") for (int n = 0; n < 2; n++) \
            gll16(A + ((size_t)((mx * 8 + c0 + n) * 24 + (t)) * 64 + l) * 8, \
                  &st.A[bu][(c0 + n) * 512]); \
        _Pragma("unroll") for (int n = 0; n < 2; n++) \
            gll16(Wtm + ((size_t)((blockIdx.y * 8 + c0 + n) * 24 + (t)) * 64 + l) * 8, \
                  &st.B[bu][(c0 + n) * 512]); }
#define GO_C(bu) { bf16x8 aq[4], bq[4]; \
        _Pragma("unroll") for (int i = 0; i < 4; i++) \
            aq[i] = *(const bf16x8*)&st.A[bu][((wm * 4 + i) * 64 + l) * 8]; \
        _Pragma("unroll") for (int j = 0; j < 4; j++) \
            bq[j] = *(const bf16x8*)&st.B[bu][((wn * 4 + j) * 64 + l) * 8]; \
        _Pragma("unroll") for (int i = 0; i < 4; i++) \
        _Pragma("unroll") for (int j = 0; j < 4; j++) \
            acc[i][j] = __builtin_amdgcn_mfma_f32_16x16x32_bf16(aq[i], bq[j], acc[i][j], 0, 0, 0); }

    GO_S(0, 0);

    for (int kt = 0; kt < DC / 32; ++kt) {
        const int cb = kt & 1, nx = cb ^ 1;
        __builtin_amdgcn_s_barrier();
        __builtin_amdgcn_sched_barrier(0);
        if (kt < 23) {
            GO_S(nx, kt + 1);
            asm volatile("s_waitcnt vmcnt(4)" ::: "memory");
        } else {
            asm volatile("s_waitcnt vmcnt(0)" ::: "memory");
        }
        __builtin_amdgcn_sched_barrier(0);
        __builtin_amdgcn_s_barrier();
        __builtin_amdgcn_sched_barrier(0);
        GO_C(cb);
    }
#undef GO_S
#undef GO_C

    float bv[4];
#pragma unroll
    for (int j = 0; j < 4; j++)
        bv[j] = bias[n0 + wn * 64 + j * 16 + lid];
#pragma unroll
    for (int i = 0; i < 4; i++)
#pragma unroll
        for (int j = 0; j < 4; j++)
#pragma unroll
            for (int r = 0; r < 4; r++) {
                int m = m0 + wm * 64 + i * 16 + qd * 4 + r;
                int f = n0 + wn * 64 + j * 16 + lid;
                out[(size_t)(rowoff + m) * DC + f] = acc[i][j][r] + bv[j];
            }
}

// ---------- MFMA flash attention: reg-prefetch double-buffered staging ----------
__global__ __launch_bounds__(256, 3) void attn_mfma(
    const uint16_t* __restrict__ Pf,
    const uint16_t* __restrict__ Pi,
    const void* __restrict__ maskp,
    const int* __restrict__ flags,
    uint16_t* __restrict__ Osv,        // swizzled visual O (M=8192)
    uint16_t* __restrict__ Osl)        // swizzled language O (M=1024)
{
    __shared__ uint16_t Klds[64 * 72];      // [key][e]
    __shared__ uint16_t Vlds[64 * 72];      // [e][key]
    __shared__ uint16_t Plds[4][16 * 72];   // per-wave P [q][key]
    __shared__ float    Ma[SC];
    __shared__ float    Lw[4][16];

    const int bh = blockIdx.x;
    const int tile = blockIdx.y;
    const int b = bh / HC, h = bh % HC;
    const int tid = threadIdx.x;
    const int w = tid >> 6, l = tid & 63;
    const int lid = l & 15, qd = l >> 4;

    const size_t SF = (size_t)BB * HC * T1C * EC;
    const size_t SI = (size_t)BB * HC * T2C * EC;

    const bool vis = (tile < 8);
    const uint16_t *Qa, *Qb, *K1, *K2, *V1, *V2;
    uint16_t* O; int Tq, q0;
    if (vis) { Qa = Pf + 1 * SF; Qb = Pf + 3 * SF; K1 = Pf;          K2 = Pi;
               V1 = Pf + 2 * SF; V2 = Pi + 1 * SI; O = Osv; Tq = T1C; q0 = tile * 64; }
    else     { Qa = Pi + 2 * SI; Qb = Pi + 3 * SI; K1 = Pf + 4 * SF; K2 = Pi + 4 * SI;
               V1 = Pf + 5 * SF; V2 = Pi + 5 * SI; O = Osl; Tq = T2C; q0 = 0; }

    {
        const int kind = flags[0];
        for (int i = tid; i < SC; i += 256) {
            int idx = b * SC + i;
            int mv;
            if (kind == 0)      mv = ((const uint32_t*)maskp)[idx] != 0u;
            else if (kind == 1) mv = ((const uint8_t*)maskp)[idx] != 0;
            else                mv = ((const uint16_t*)maskp)[idx] != 0;
            Ma[i] = mv ? -1e9f : 0.0f;
        }
    }

    // preload BOTH Q variants (the 9th chunk switches query matrix)
    const int q = q0 + w * 16 + lid;
    const uint16_t* Qrow  = Qa + ((size_t)bh * Tq + q) * EC;
    const uint16_t* Qrow2 = Qb + ((size_t)bh * Tq + q) * EC;
    bf16x8 qf0 = *(const bf16x8*)(Qrow + qd * 8);
    bf16x8 qf1 = *(const bf16x8*)(Qrow + 32 + qd * 8);
    bf16x8 qg0 = *(const bf16x8*)(Qrow2 + qd * 8);
    bf16x8 qg1 = *(const bf16x8*)(Qrow2 + 32 + qd * 8);

    f32x4 o[4];
#pragma unroll
    for (int ef = 0; ef < 4; ef++) { o[ef][0]=0.f; o[ef][1]=0.f; o[ef][2]=0.f; o[ef][3]=0.f; }
    float u[4] = {0.f, 0.f, 0.f, 0.f};

    const int skey = tid >> 2, se0 = (tid & 3) * 16;   // K stage (row, col chunk)
    const int ve = tid >> 2,  vc = tid & 3;            // V stage (e-row, key chunk)

    // chunk-c staging source addresses (c compile-time under full unroll)
    auto kptr = [&](int c) -> const uint16_t* {
        return (c < 8) ? K1 + ((size_t)bh * T1C + c * 64 + skey) * EC + se0
                       : K2 + ((size_t)bh * T2C + skey) * EC + se0;
    };
    auto vptr = [&](int c) -> const uint16_t* {
        return (c < 8) ? V1 + ((size_t)bh * EC + ve) * T1C + c * 64 + vc * 16
                       : V2 + ((size_t)bh * EC + ve) * T2C + vc * 16;
    };

    // prologue: issue chunk 0 loads into current regs
    uint4 ka0 = *(const uint4*)kptr(0);
    uint4 ka1 = *(const uint4*)(kptr(0) + 8);
    uint4 va0 = *(const uint4*)vptr(0);
    uint4 va1 = *(const uint4*)(vptr(0) + 8);

#pragma unroll
    for (int c = 0; c < 9; ++c) {
        // issue next chunk's loads FIRST (newer in vmcnt order; the compiler's
        // auto-wait before the ds_writes below then only drains chunk c's loads)
        uint4 kb0, kb1, vb0, vb1;
        if (c < 8) {
            kb0 = *(const uint4*)kptr(c + 1);
            kb1 = *(const uint4*)(kptr(c + 1) + 8);
            vb0 = *(const uint4*)vptr(c + 1);
            vb1 = *(const uint4*)(vptr(c + 1) + 8);
        }
        __builtin_amdgcn_s_barrier();              // prev chunk LDS reads done
        __builtin_amdgcn_sched_barrier(0);
        *(uint4*)&Klds[skey * 72 + se0]         = ka0;
        *(uint4*)&Klds[skey * 72 + se0 + 8]     = ka1;
        *(uint4*)&Vlds[ve * 72 + vc * 16]       = va0;
        *(uint4*)&Vlds[ve * 72 + vc * 16 + 8]   = va1;
        asm volatile("s_waitcnt lgkmcnt(0)" ::: "memory");
        __builtin_amdgcn_sched_barrier(0);
        __builtin_amdgcn_s_barrier();              // publish K/V (and Ma @c=0)
        __builtin_amdgcn_sched_barrier(0);

        const int k0 = c * 64;
        const bf16x8 q_0 = (c < 8) ? qf0 : qg0;
        const bf16x8 q_1 = (c < 8) ? qf1 : qg1;
        // QK^T: D[q][key]
        f32x4 s[4];
#pragma unroll
        for (int sub = 0; sub < 4; sub++) {
            bf16x8 kf0 = *(const bf16x8*)&Klds[(sub * 16 + lid) * 72 + qd * 8];
            bf16x8 kf1 = *(const bf16x8*)&Klds[(sub * 16 + lid) * 72 + 32 + qd * 8];
            f32x4 z; z[0]=0.f; z[1]=0.f; z[2]=0.f; z[3]=0.f;
            z = __builtin_amdgcn_mfma_f32_16x16x32_bf16(q_0, kf0, z, 0, 0, 0);
            s[sub] = __builtin_amdgcn_mfma_f32_16x16x32_bf16(q_1, kf1, z, 0, 0, 0);
        }
        // p = exp(s + mask); accumulate row-sum; write P (C-layout -> [q][key])
#pragma unroll
        for (int sub = 0; sub < 4; sub++) {
            float mv = Ma[k0 + sub * 16 + lid];
#pragma unroll
            for (int r = 0; r < 4; r++) {
                float p = __expf(s[sub][r] + mv);
                u[r] += p;
                Plds[w][(qd * 4 + r) * 72 + sub * 16 + lid] = f2bfast(p);
            }
        }
        // PV as O^T = Vt * P^T (wave-local Plds round trip, no barrier)
#pragma unroll
        for (int half = 0; half < 2; half++) {
            bf16x8 pf = *(const bf16x8*)&Plds[w][lid * 72 + half * 32 + qd * 8];
#pragma unroll
            for (int ef = 0; ef < 4; ef++) {
                bf16x8 vf = *(const bf16x8*)&Vlds[(ef * 16 + lid) * 72 + half * 32 + qd * 8];
                o[ef] = __builtin_amdgcn_mfma_f32_16x16x32_bf16(vf, pf, o[ef], 0, 0, 0);
            }
        }
        if (c < 8) { ka0 = kb0; ka1 = kb1; va0 = vb0; va1 = vb1; }
    }

    // one-time row-sum reduction across key-lanes (bits 0-3)
#pragma unroll
    for (int d = 1; d <= 8; d <<= 1)
#pragma unroll
        for (int r = 0; r < 4; r++)
            u[r] += __shfl_xor(u[r], d, 64);
    if (lid == 0) {
#pragma unroll
        for (int r = 0; r < 4; r++) Lw[w][qd * 4 + r] = u[r];
    }
    float rl = 1.f / Lw[w][lid];   // l for this lane's query (wave-local ordering)

    // O write in gemm_out's swizzled A-frag order:
    // m = b*Tq + q; panel p = m>>4 (wave-uniform), rlid = lid.
    // col = h*64 + e, e = ef*16 + qd*4 + r  ->  kt = h*2 + (ef>>1),
    // cq = (ef&1)*2 + (qd>>1), j = (qd&1)*4 + r  -> one 8B store per ef.
    const size_t p = ((size_t)b * Tq + q0 + w * 16) >> 4;
#pragma unroll
    for (int ef = 0; ef < 4; ef++) {
        uint32_t w0 = pk2(o[ef][0] * rl, o[ef][1] * rl);
        uint32_t w1 = pk2(o[ef][2] * rl, o[ef][3] * rl);
        size_t chunk = ((p * 24 + h * 2 + (ef >> 1)) * 4 + (ef & 1) * 2 + (qd >> 1)) * 16 + lid;
        *(uint2*)(O + chunk * 8 + (qd & 1) * 4) = make_uint2(w0, w1);
    }
}

// ---------- launch ----------
extern "C" void kernel_launch(void* const* d_in, const int* in_sizes, int n_in,
                              void* d_out, int out_size, void* d_ws, size_t ws_size,
                              hipStream_t stream)
{
    const float* feats = (const float*)d_in[0];
    const float* inps  = (const float*)d_in[1];
    const void*  maskp = d_in[2];
    const float* W_f   = (const float*)d_in[3];
    const float* b_f   = (const float*)d_in[4];
    const float* W_i   = (const float*)d_in[5];
    const float* b_i   = (const float*)d_in[6];
    const float* Wu_v  = (const float*)d_in[7];
    const float* bu_v  = (const float*)d_in[8];
    const float* Wu_l  = (const float*)d_in[9];
    const float* bu_l  = (const float*)d_in[10];

    const size_t MAT = (size_t)DC * DC;               // 589824
    const size_t PF_E = 6ull * BB * HC * T1C * EC;
    const size_t PI_E = 6ull * BB * HC * T2C * EC;
    uint16_t* Wt  = (uint16_t*)d_ws;
    uint16_t* Osv = Wt;                               // reuses dead Wt[0..11]
    uint16_t* Osl = Wt + (size_t)BB * T1C * HC * EC;
    uint16_t* Pf  = Wt + 14 * MAT;
    uint16_t* Pi  = Pf + PF_E;
    int* flags    = (int*)(Pi + PI_E);

    // Swizzled bf16 X lives in d_out's first ~21 MB: d_out is only written by
    // the final gemm_out launch (stream-ordered after all Xs reads).
    uint16_t* Xsf = (uint16_t*)d_out;
    uint16_t* Xsi = Xsf + (size_t)BB * T1C * DC;

    prep<<<dim3(WT_BLOCKS + XS_BLOCKS + 1), dim3(256), 0, stream>>>(
        W_f, W_i, Wu_v, Wu_l, Wt, feats, inps, Xsf, Xsi,
        (const uint32_t*)maskp, flags);

    gemm_proj_mfma<<<dim3(72, 18), dim3(256), 0, stream>>>(
        Xsf, Xsi, Wt, b_f, b_i, Pf, Pi);

    attn_mfma<<<dim3(BB * HC, 9), dim3(256), 0, stream>>>(
        Pf, Pi, maskp, flags, Osv, Osl);

    gemm_out_mfma<<<dim3(72, 6), dim3(256), 0, stream>>>(
        Osv, Osl, Wt, bu_v, bu_l, (float*)d_out);
}

// Round 9
// 245.594 us; speedup vs baseline: 1.5230x; 1.5230x over previous
//
#include <hip/hip_runtime.h>
#include <stdint.h>

// Problem constants
#define BB 16
#define T1C 512
#define T2C 64
#define DC 768
#define HC 12
#define EC 64
#define SC 576          // T1+T2
#define QSCALE 0.35355339059327379f   // 64^-0.25

typedef __attribute__((ext_vector_type(8))) short bf16x8;   // 8 bf16 = 4 VGPRs
typedef __attribute__((ext_vector_type(4))) float f32x4;    // MFMA C/D

// ---------- bf16 helpers ----------
__device__ __forceinline__ uint16_t f2b(float f) {          // RNE
    union { float f; uint32_t i; } v; v.f = f;
    return (uint16_t)((v.i + 0x7fffu + ((v.i >> 16) & 1u)) >> 16);
}
__device__ __forceinline__ uint16_t f2bfast(float f) {      // round-half-up (cheap)
    union { float f; uint32_t i; } v; v.f = f;
    return (uint16_t)((v.i + 0x8000u) >> 16);
}
__device__ __forceinline__ uint32_t pk2(float a, float b) {
    return (uint32_t)f2b(a) | ((uint32_t)f2b(b) << 16);
}

// async global->LDS, 16B per lane; LDS dest = wave-uniform base + lane*16
__device__ __forceinline__ void gll16(const void* g, void* l) {
    __builtin_amdgcn_global_load_lds(
        (const __attribute__((address_space(1))) uint32_t*)(uintptr_t)g,
        (__attribute__((address_space(3))) uint32_t*)(uintptr_t)l, 16, 0, 0);
}

#define WT_BLOCKS (24 * 24 * 14)   // 8064 wtrans blocks
#define XS_BLOCKS 3456             // 884736 chunks / 256

// ---------- fused prep: wtrans + xswz + detect in ONE launch ----------
// wtrans emits Wt[z] in CHUNK order (same frag layout as Xs):
//   chunk cc = ((p*24 + kt)*4 + qd)*16 + rlid, p = f>>4, rlid = f&15,
//   holding W_z[kt*32+qd*8 .. +7][p*16+rlid].
__global__ __launch_bounds__(256) void prep(
    const float* __restrict__ Wf, const float* __restrict__ Wi,
    const float* __restrict__ Wuv, const float* __restrict__ Wul,
    uint16_t* __restrict__ Wt,
    const float* __restrict__ Xf, const float* __restrict__ Xi,
    uint16_t* __restrict__ Of, uint16_t* __restrict__ Oi,
    const uint32_t* __restrict__ mw, int* __restrict__ flags)
{
    __shared__ union { float tile[32][33]; int d[3]; } sh;
    const int bid = blockIdx.x;
    if (bid < WT_BLOCKS) {
        // ---- weight transpose + f32->bf16 -> chunk-order Wt ----
        const int z = bid / 576, r = bid % 576;
        const int kx = r % 24, fy = r / 24;      // k-tile kt = kx, f block = fy*32
        const float* src = (z < 6)  ? Wf + (size_t)z * DC * DC
                         : (z < 12) ? Wi + (size_t)(z - 6) * DC * DC
                         : (z == 12 ? Wuv : Wul);
        uint16_t* dst = Wt + (size_t)z * DC * DC;
        const int tx = threadIdx.x & 31, ty = threadIdx.x >> 5;
        const int k0 = kx * 32, f0 = fy * 32;
#pragma unroll
        for (int q = 0; q < 4; q++)
            sh.tile[ty + q * 8][tx] = src[(size_t)(k0 + ty + q * 8) * DC + f0 + tx];
        __syncthreads();
        if (threadIdx.x < 128) {
            const int fl = threadIdx.x & 31, kg = threadIdx.x >> 5;  // f lane, qd
            const int p = (f0 + fl) >> 4, rlid = fl & 15;
            uint4 o;
            o.x = pk2(sh.tile[kg * 8 + 0][fl], sh.tile[kg * 8 + 1][fl]);
            o.y = pk2(sh.tile[kg * 8 + 2][fl], sh.tile[kg * 8 + 3][fl]);
            o.z = pk2(sh.tile[kg * 8 + 4][fl], sh.tile[kg * 8 + 5][fl]);
            o.w = pk2(sh.tile[kg * 8 + 6][fl], sh.tile[kg * 8 + 7][fl]);
            *(uint4*)(dst + ((size_t)((p * 24 + kx) * 4 + kg) * 16 + rlid) * 8) = o;
        }
    } else if (bid < WT_BLOCKS + XS_BLOCKS) {
        // ---- X f32 -> bf16 swizzle (MFMA A-fragment order) ----
        const int nf = BB * T1C * DC / 8;
        const int ni = BB * T2C * DC / 8;
        int t = (bid - WT_BLOCKS) * 256 + threadIdx.x;
        const float* src; uint16_t* dst; int cc;
        if (t < nf) { src = Xf; dst = Of; cc = t; }
        else        { cc = t - nf; if (cc >= ni) return; src = Xi; dst = Oi; }
        int rlid = cc & 15;
        int t2 = cc >> 4;
        int qd = t2 & 3;
        int t3 = t2 >> 2;
        int kt = t3 % 24;
        int p  = t3 / 24;
        const float* sp = src + (size_t)(p * 16 + rlid) * DC + kt * 32 + qd * 8;
        float4 a = *(const float4*)sp;
        float4 b = *(const float4*)(sp + 4);
        uint4 o;
        o.x = pk2(a.x, a.y); o.y = pk2(a.z, a.w);
        o.z = pk2(b.x, b.y); o.w = pk2(b.z, b.w);
        *(uint4*)(dst + (size_t)cc * 8) = o;
    } else {
        // ---- mask layout detect (deterministic -> graph-safe) ----
        if (threadIdx.x == 0) { sh.d[0] = 0; sh.d[1] = 0; sh.d[2] = 0; }
        __syncthreads();
        int lW = 0, lB = 0, lL = 0;
        for (int i = threadIdx.x; i < 2304; i += 256) {
            uint32_t w = mw[i];
            if (w > 1u) lW = 1;
            if (((w) & 0xffu) > 1u || ((w >> 8) & 0xffu) > 1u ||
                ((w >> 16) & 0xffu) > 1u || ((w >> 24) & 0xffu) > 1u) lB = 1;
            if ((w & 0xffffu) > 1u) lL = 1;
        }
        if (lW) atomicOr(&sh.d[0], 1);
        if (lB) atomicOr(&sh.d[1], 1);
        if (lL) atomicOr(&sh.d[2], 1);
        __syncthreads();
        if (threadIdx.x == 0)
            flags[0] = (!sh.d[0]) ? 0 : ((!sh.d[1]) ? 1 : (sh.d[2] ? 2 : 0));
    }
}

#define BSTR 76   // epilogue bounce stride (bf16 elems), conflict-free

// ---------- MFMA projection GEMM: 128x256 block, 64x128 wave tiles ----------
// 4 waves (2m x 2n), BK=32, chunk-order A+B double-buffered LDS (48 KB),
// counted vmcnt(6). __launch_bounds__(256,2): ~256-reg cap so the 128-AGPR
// accumulator + working set (~212 regs) fits WITHOUT spill (R8's (256,3)
// ~170-reg cap spilled acc -> 411MB scratch writes, 215us). At 2 blocks/CU
// the LDS-read pipe stays saturated (8 waves x 12KB = 96KB/round, same as
// R7's 12x8KB) while FLOPs/round rise 1.33x -> LDS-bound model predicts
// ~60-66us vs R7's 80.
__global__ __launch_bounds__(256, 2) void gemm_proj_mfma(
    const uint16_t* __restrict__ Xsf, const uint16_t* __restrict__ Xsi,
    const uint16_t* __restrict__ Wt,
    const float* __restrict__ b_f, const float* __restrict__ b_i,
    uint16_t* __restrict__ Pf, uint16_t* __restrict__ Pi)
{
    __shared__ union {
        struct { uint16_t A[2][128 * 32]; uint16_t B[2][256 * 32]; } st; // 48 KB
        uint16_t bounce[4][16 * BSTR];        // 9.5 KB epilogue
    } sm;
    const int tid = threadIdx.x;
    const int w = tid >> 6, l = tid & 63;
    const bool isf = (blockIdx.x < 64);
    const int mx = isf ? blockIdx.x : blockIdx.x - 64;
    const int m0 = mx * 128;
    const int T  = isf ? T1C : T2C;
    const uint16_t* Xs = isf ? Xsf : Xsi;
    const float* bias  = isf ? b_f : b_i;
    uint16_t* P        = isf ? Pf : Pi;
    const int vmask    = isf ? 0x24 : 0x22;
    const int k6 = blockIdx.y / 3, nb = blockIdx.y % 3;
    const int n0 = nb * 256;
    const uint16_t* Bsrc = Wt + (size_t)((isf ? 0 : 6) + k6) * DC * DC;

    const int lid = l & 15, qd = l >> 4;
    const int wm = w >> 1, wn = w & 1;

    f32x4 acc[4][8] = {};

    // stage tile t: A panels mx*8 + w*2+{0,1}; B panels nb*16 + w*4+{0..3}
#define PJ_S(bu, t) { \
        _Pragma("unroll") for (int n = 0; n < 2; n++) \
            gll16(Xs + ((size_t)((mx * 8 + w * 2 + n) * 24 + (t)) * 64 + l) * 8, \
                  &sm.st.A[bu][(w * 2 + n) * 512]); \
        _Pragma("unroll") for (int n = 0; n < 4; n++) \
            gll16(Bsrc + ((size_t)((nb * 16 + w * 4 + n) * 24 + (t)) * 64 + l) * 8, \
                  &sm.st.B[bu][(w * 4 + n) * 512]); }
#define PJ_C(bu) { bf16x8 aq[4], bq[8]; \
        _Pragma("unroll") for (int i = 0; i < 4; i++) \
            aq[i] = *(const bf16x8*)&sm.st.A[bu][((wm * 4 + i) * 64 + l) * 8]; \
        _Pragma("unroll") for (int j = 0; j < 8; j++) \
            bq[j] = *(const bf16x8*)&sm.st.B[bu][((wn * 8 + j) * 64 + l) * 8]; \
        _Pragma("unroll") for (int i = 0; i < 4; i++) \
        _Pragma("unroll") for (int j = 0; j < 8; j++) \
            acc[i][j] = __builtin_amdgcn_mfma_f32_16x16x32_bf16(aq[i], bq[j], acc[i][j], 0, 0, 0); }

    PJ_S(0, 0);                                // prologue: tile 0 in flight (6)

    for (int kt = 0; kt < DC / 32; ++kt) {
        const int cb = kt & 1, nx = cb ^ 1;
        __builtin_amdgcn_s_barrier();          // all waves done reading buf nx
        __builtin_amdgcn_sched_barrier(0);
        if (kt < 23) {
            PJ_S(nx, kt + 1);                  // outstanding: S(t)6 + S(t+1)6
            asm volatile("s_waitcnt vmcnt(6)" ::: "memory");  // retire S(t)
        } else {
            asm volatile("s_waitcnt vmcnt(0)" ::: "memory");  // final drain
        }
        __builtin_amdgcn_sched_barrier(0);
        __builtin_amdgcn_s_barrier();          // publish tile kt cross-wave
        __builtin_amdgcn_sched_barrier(0);
        PJ_C(cb);
    }
#undef PJ_S
#undef PJ_C

    float bv[8];
#pragma unroll
    for (int j = 0; j < 8; j++)
        bv[j] = bias[k6 * DC + n0 + wn * 128 + j * 16 + lid];
    __syncthreads();   // all waves' K-loop LDS reads done before bounce overwrite

    uint16_t* reg = sm.bounce[w];
    const int mb = m0 + wm * 64;
    const int b = mb / T, tb = mb - b * T;     // 64-row wave tile never crosses b
    const int rrow = l >> 2;                   // readback row within pass
    const int rcol = (l & 3) * 16;             // readback col chunk

    if (!((vmask >> k6) & 1)) {
        // normal [t][e]: per head hl, pass p = m-rows p*16..+15 (i = p)
#pragma unroll
        for (int hl = 0; hl < 2; hl++) {
            const int h = nb * 4 + wn * 2 + hl;
            uint16_t* dst0 = P + ((((size_t)k6 * BB + b) * HC + h) * T + tb + rrow) * EC + rcol;
#pragma unroll
            for (int p = 0; p < 4; p++) {
#pragma unroll
                for (int jj = 0; jj < 4; jj++)
#pragma unroll
                    for (int r = 0; r < 4; r++)
                        reg[(qd * 4 + r) * BSTR + jj * 16 + lid] =
                            f2b((acc[p][hl * 4 + jj][r] + bv[hl * 4 + jj]) * QSCALE);
                uint4 d0 = *(const uint4*)&reg[rrow * BSTR + rcol];
                uint4 d1 = *(const uint4*)&reg[rrow * BSTR + rcol + 8];
                uint16_t* dst = dst0 + (size_t)p * 16 * EC;
                *(uint4*)dst = d0;
                *(uint4*)(dst + 8) = d1;
            }
        }
    } else {
        // transposed [e][t]: per head hl, pass p = e-rows p*16..+15 (j = hl*4+p)
#pragma unroll
        for (int hl = 0; hl < 2; hl++) {
            const int h = nb * 4 + wn * 2 + hl;
            uint16_t* dst0 = P + (size_t)k6 * BB * HC * T * EC
                               + (((size_t)b * HC + h) * EC + rrow) * T + tb + rcol;
#pragma unroll
            for (int p = 0; p < 4; p++) {
#pragma unroll
                for (int i = 0; i < 4; i++) {
                    uint32_t w0 = pk2((acc[i][hl * 4 + p][0] + bv[hl * 4 + p]) * QSCALE,
                                      (acc[i][hl * 4 + p][1] + bv[hl * 4 + p]) * QSCALE);
                    uint32_t w1 = pk2((acc[i][hl * 4 + p][2] + bv[hl * 4 + p]) * QSCALE,
                                      (acc[i][hl * 4 + p][3] + bv[hl * 4 + p]) * QSCALE);
                    *(uint2*)&reg[lid * BSTR + i * 16 + qd * 4] = make_uint2(w0, w1);
                }
                uint4 d0 = *(const uint4*)&reg[rrow * BSTR + rcol];
                uint4 d1 = *(const uint4*)&reg[rrow * BSTR + rcol + 8];
                uint16_t* dst = dst0 + (size_t)p * 16 * T;
                *(uint4*)dst = d0;
                *(uint4*)(dst + 8) = d1;
            }
        }
    }
}

// ---------- MFMA output GEMM: R6 chunk-order both-staged schedule ----------
__global__ __launch_bounds__(256, 4) void gemm_out_mfma(
    const uint16_t* __restrict__ Osv, const uint16_t* __restrict__ Osl,
    const uint16_t* __restrict__ Wt,
    const float* __restrict__ bu_v, const float* __restrict__ bu_l,
    float* __restrict__ out)
{
    __shared__ struct { uint16_t A[2][128 * 32]; uint16_t B[2][128 * 32]; } st;
    const int tid = threadIdx.x;
    const int w = tid >> 6, l = tid & 63;
    const bool isv = (blockIdx.x < 64);
    const int mx = isv ? blockIdx.x : blockIdx.x - 64;
    const int m0 = mx * 128;
    const int rowoff = isv ? 0 : BB * T1C;
    const uint16_t* A = isv ? Osv : Osl;
    const uint16_t* Wtm = Wt + (size_t)(isv ? 12 : 13) * DC * DC;
    const float* bias = isv ? bu_v : bu_l;
    const int n0 = blockIdx.y * 128;
    const int lid = l & 15, qd = l >> 4;
    const int wm = w >> 1, wn = w & 1;
    const int c0 = w * 2;

    f32x4 acc[4][4] = {};

#define GO_S(bu, t) { \
        _Pragma("unroll") for (int n = 0; n < 2; n++) \
            gll16(A + ((size_t)((mx * 8 + c0 + n) * 24 + (t)) * 64 + l) * 8, \
                  &st.A[bu][(c0 + n) * 512]); \
        _Pragma("unroll") for (int n = 0; n < 2; n++) \
            gll16(Wtm + ((size_t)((blockIdx.y * 8 + c0 + n) * 24 + (t)) * 64 + l) * 8, \
                  &st.B[bu][(c0 + n) * 512]); }
#define GO_C(bu) { bf16x8 aq[4], bq[4]; \
        _Pragma("unroll") for (int i = 0; i < 4; i++) \
            aq[i] = *(const bf16x8*)&st.A[bu][((wm * 4 + i) * 64 + l) * 8]; \
        _Pragma("unroll") for (int j = 0; j < 4; j++) \
            bq[j] = *(const bf16x8*)&st.B[bu][((wn * 4 + j) * 64 + l) * 8]; \
        _Pragma("unroll") for (int i = 0; i < 4; i++) \
        _Pragma("unroll") for (int j = 0; j < 4; j++) \
            acc[i][j] = __builtin_amdgcn_mfma_f32_16x16x32_bf16(aq[i], bq[j], acc[i][j], 0, 0, 0); }

    GO_S(0, 0);

    for (int kt = 0; kt < DC / 32; ++kt) {
        const int cb = kt & 1, nx = cb ^ 1;
        __builtin_amdgcn_s_barrier();
        __builtin_amdgcn_sched_barrier(0);
        if (kt < 23) {
            GO_S(nx, kt + 1);
            asm volatile("s_waitcnt vmcnt(4)" ::: "memory");
        } else {
            asm volatile("s_waitcnt vmcnt(0)" ::: "memory");
        }
        __builtin_amdgcn_sched_barrier(0);
        __builtin_amdgcn_s_barrier();
        __builtin_amdgcn_sched_barrier(0);
        GO_C(cb);
    }
#undef GO_S
#undef GO_C

    float bv[4];
#pragma unroll
    for (int j = 0; j < 4; j++)
        bv[j] = bias[n0 + wn * 64 + j * 16 + lid];
#pragma unroll
    for (int i = 0; i < 4; i++)
#pragma unroll
        for (int j = 0; j < 4; j++)
#pragma unroll
            for (int r = 0; r < 4; r++) {
                int m = m0 + wm * 64 + i * 16 + qd * 4 + r;
                int f = n0 + wn * 64 + j * 16 + lid;
                out[(size_t)(rowoff + m) * DC + f] = acc[i][j][r] + bv[j];
            }
}

// ---------- MFMA flash attention: reg-prefetch double-buffered staging ----------
__global__ __launch_bounds__(256, 3) void attn_mfma(
    const uint16_t* __restrict__ Pf,
    const uint16_t* __restrict__ Pi,
    const void* __restrict__ maskp,
    const int* __restrict__ flags,
    uint16_t* __restrict__ Osv,        // swizzled visual O (M=8192)
    uint16_t* __restrict__ Osl)        // swizzled language O (M=1024)
{
    __shared__ uint16_t Klds[64 * 72];      // [key][e]
    __shared__ uint16_t Vlds[64 * 72];      // [e][key]
    __shared__ uint16_t Plds[4][16 * 72];   // per-wave P [q][key]
    __shared__ float    Ma[SC];
    __shared__ float    Lw[4][16];

    const int bh = blockIdx.x;
    const int tile = blockIdx.y;
    const int b = bh / HC, h = bh % HC;
    const int tid = threadIdx.x;
    const int w = tid >> 6, l = tid & 63;
    const int lid = l & 15, qd = l >> 4;

    const size_t SF = (size_t)BB * HC * T1C * EC;
    const size_t SI = (size_t)BB * HC * T2C * EC;

    const bool vis = (tile < 8);
    const uint16_t *Qa, *Qb, *K1, *K2, *V1, *V2;
    uint16_t* O; int Tq, q0;
    if (vis) { Qa = Pf + 1 * SF; Qb = Pf + 3 * SF; K1 = Pf;          K2 = Pi;
               V1 = Pf + 2 * SF; V2 = Pi + 1 * SI; O = Osv; Tq = T1C; q0 = tile * 64; }
    else     { Qa = Pi + 2 * SI; Qb = Pi + 3 * SI; K1 = Pf + 4 * SF; K2 = Pi + 4 * SI;
               V1 = Pf + 5 * SF; V2 = Pi + 5 * SI; O = Osl; Tq = T2C; q0 = 0; }

    {
        const int kind = flags[0];
        for (int i = tid; i < SC; i += 256) {
            int idx = b * SC + i;
            int mv;
            if (kind == 0)      mv = ((const uint32_t*)maskp)[idx] != 0u;
            else if (kind == 1) mv = ((const uint8_t*)maskp)[idx] != 0;
            else                mv = ((const uint16_t*)maskp)[idx] != 0;
            Ma[i] = mv ? -1e9f : 0.0f;
        }
    }

    // preload BOTH Q variants (the 9th chunk switches query matrix)
    const int q = q0 + w * 16 + lid;
    const uint16_t* Qrow  = Qa + ((size_t)bh * Tq + q) * EC;
    const uint16_t* Qrow2 = Qb + ((size_t)bh * Tq + q) * EC;
    bf16x8 qf0 = *(const bf16x8*)(Qrow + qd * 8);
    bf16x8 qf1 = *(const bf16x8*)(Qrow + 32 + qd * 8);
    bf16x8 qg0 = *(const bf16x8*)(Qrow2 + qd * 8);
    bf16x8 qg1 = *(const bf16x8*)(Qrow2 + 32 + qd * 8);

    f32x4 o[4];
#pragma unroll
    for (int ef = 0; ef < 4; ef++) { o[ef][0]=0.f; o[ef][1]=0.f; o[ef][2]=0.f; o[ef][3]=0.f; }
    float u[4] = {0.f, 0.f, 0.f, 0.f};

    const int skey = tid >> 2, se0 = (tid & 3) * 16;   // K stage (row, col chunk)
    const int ve = tid >> 2,  vc = tid & 3;            // V stage (e-row, key chunk)

    // chunk-c staging source addresses (c compile-time under full unroll)
    auto kptr = [&](int c) -> const uint16_t* {
        return (c < 8) ? K1 + ((size_t)bh * T1C + c * 64 + skey) * EC + se0
                       : K2 + ((size_t)bh * T2C + skey) * EC + se0;
    };
    auto vptr = [&](int c) -> const uint16_t* {
        return (c < 8) ? V1 + ((size_t)bh * EC + ve) * T1C + c * 64 + vc * 16
                       : V2 + ((size_t)bh * EC + ve) * T2C + vc * 16;
    };

    // prologue: issue chunk 0 loads into current regs
    uint4 ka0 = *(const uint4*)kptr(0);
    uint4 ka1 = *(const uint4*)(kptr(0) + 8);
    uint4 va0 = *(const uint4*)vptr(0);
    uint4 va1 = *(const uint4*)(vptr(0) + 8);

#pragma unroll
    for (int c = 0; c < 9; ++c) {
        // issue next chunk's loads FIRST (newer in vmcnt order; the compiler's
        // auto-wait before the ds_writes below then only drains chunk c's loads)
        uint4 kb0, kb1, vb0, vb1;
        if (c < 8) {
            kb0 = *(const uint4*)kptr(c + 1);
            kb1 = *(const uint4*)(kptr(c + 1) + 8);
            vb0 = *(const uint4*)vptr(c + 1);
            vb1 = *(const uint4*)(vptr(c + 1) + 8);
        }
        __builtin_amdgcn_s_barrier();              // prev chunk LDS reads done
        __builtin_amdgcn_sched_barrier(0);
        *(uint4*)&Klds[skey * 72 + se0]         = ka0;
        *(uint4*)&Klds[skey * 72 + se0 + 8]     = ka1;
        *(uint4*)&Vlds[ve * 72 + vc * 16]       = va0;
        *(uint4*)&Vlds[ve * 72 + vc * 16 + 8]   = va1;
        asm volatile("s_waitcnt lgkmcnt(0)" ::: "memory");
        __builtin_amdgcn_sched_barrier(0);
        __builtin_amdgcn_s_barrier();              // publish K/V (and Ma @c=0)
        __builtin_amdgcn_sched_barrier(0);

        const int k0 = c * 64;
        const bf16x8 q_0 = (c < 8) ? qf0 : qg0;
        const bf16x8 q_1 = (c < 8) ? qf1 : qg1;
        // QK^T: D[q][key]
        f32x4 s[4];
#pragma unroll
        for (int sub = 0; sub < 4; sub++) {
            bf16x8 kf0 = *(const bf16x8*)&Klds[(sub * 16 + lid) * 72 + qd * 8];
            bf16x8 kf1 = *(const bf16x8*)&Klds[(sub * 16 + lid) * 72 + 32 + qd * 8];
            f32x4 z; z[0]=0.f; z[1]=0.f; z[2]=0.f; z[3]=0.f;
            z = __builtin_amdgcn_mfma_f32_16x16x32_bf16(q_0, kf0, z, 0, 0, 0);
            s[sub] = __builtin_amdgcn_mfma_f32_16x16x32_bf16(q_1, kf1, z, 0, 0, 0);
        }
        // p = exp(s + mask); accumulate row-sum; write P (C-layout -> [q][key])
#pragma unroll
        for (int sub = 0; sub < 4; sub++) {
            float mv = Ma[k0 + sub * 16 + lid];
#pragma unroll
            for (int r = 0; r < 4; r++) {
                float p = __expf(s[sub][r] + mv);
                u[r] += p;
                Plds[w][(qd * 4 + r) * 72 + sub * 16 + lid] = f2bfast(p);
            }
        }
        // PV as O^T = Vt * P^T (wave-local Plds round trip, no barrier)
#pragma unroll
        for (int half = 0; half < 2; half++) {
            bf16x8 pf = *(const bf16x8*)&Plds[w][lid * 72 + half * 32 + qd * 8];
#pragma unroll
            for (int ef = 0; ef < 4; ef++) {
                bf16x8 vf = *(const bf16x8*)&Vlds[(ef * 16 + lid) * 72 + half * 32 + qd * 8];
                o[ef] = __builtin_amdgcn_mfma_f32_16x16x32_bf16(vf, pf, o[ef], 0, 0, 0);
            }
        }
        if (c < 8) { ka0 = kb0; ka1 = kb1; va0 = vb0; va1 = vb1; }
    }

    // one-time row-sum reduction across key-lanes (bits 0-3)
#pragma unroll
    for (int d = 1; d <= 8; d <<= 1)
#pragma unroll
        for (int r = 0; r < 4; r++)
            u[r] += __shfl_xor(u[r], d, 64);
    if (lid == 0) {
#pragma unroll
        for (int r = 0; r < 4; r++) Lw[w][qd * 4 + r] = u[r];
    }
    float rl = 1.f / Lw[w][lid];   // l for this lane's query (wave-local ordering)

    // O write in gemm_out's swizzled A-frag order:
    // m = b*Tq + q; panel p = m>>4 (wave-uniform), rlid = lid.
    // col = h*64 + e, e = ef*16 + qd*4 + r  ->  kt = h*2 + (ef>>1),
    // cq = (ef&1)*2 + (qd>>1), j = (qd&1)*4 + r  -> one 8B store per ef.
    const size_t p = ((size_t)b * Tq + q0 + w * 16) >> 4;
#pragma unroll
    for (int ef = 0; ef < 4; ef++) {
        uint32_t w0 = pk2(o[ef][0] * rl, o[ef][1] * rl);
        uint32_t w1 = pk2(o[ef][2] * rl, o[ef][3] * rl);
        size_t chunk = ((p * 24 + h * 2 + (ef >> 1)) * 4 + (ef & 1) * 2 + (qd >> 1)) * 16 + lid;
        *(uint2*)(O + chunk * 8 + (qd & 1) * 4) = make_uint2(w0, w1);
    }
}

// ---------- launch ----------
extern "C" void kernel_launch(void* const* d_in, const int* in_sizes, int n_in,
                              void* d_out, int out_size, void* d_ws, size_t ws_size,
                              hipStream_t stream)
{
    const float* feats = (const float*)d_in[0];
    const float* inps  = (const float*)d_in[1];
    const void*  maskp = d_in[2];
    const float* W_f   = (const float*)d_in[3];
    const float* b_f   = (const float*)d_in[4];
    const float* W_i   = (const float*)d_in[5];
    const float* b_i   = (const float*)d_in[6];
    const float* Wu_v  = (const float*)d_in[7];
    const float* bu_v  = (const float*)d_in[8];
    const float* Wu_l  = (const float*)d_in[9];
    const float* bu_l  = (const float*)d_in[10];

    const size_t MAT = (size_t)DC * DC;               // 589824
    const size_t PF_E = 6ull * BB * HC * T1C * EC;
    const size_t PI_E = 6ull * BB * HC * T2C * EC;
    uint16_t* Wt  = (uint16_t*)d_ws;
    uint16_t* Osv = Wt;                               // reuses dead Wt[0..11]
    uint16_t* Osl = Wt + (size_t)BB * T1C * HC * EC;
    uint16_t* Pf  = Wt + 14 * MAT;
    uint16_t* Pi  = Pf + PF_E;
    int* flags    = (int*)(Pi + PI_E);

    // Swizzled bf16 X lives in d_out's first ~21 MB: d_out is only written by
    // the final gemm_out launch (stream-ordered after all Xs reads).
    uint16_t* Xsf = (uint16_t*)d_out;
    uint16_t* Xsi = Xsf + (size_t)BB * T1C * DC;

    prep<<<dim3(WT_BLOCKS + XS_BLOCKS + 1), dim3(256), 0, stream>>>(
        W_f, W_i, Wu_v, Wu_l, Wt, feats, inps, Xsf, Xsi,
        (const uint32_t*)maskp, flags);

    gemm_proj_mfma<<<dim3(72, 18), dim3(256), 0, stream>>>(
        Xsf, Xsi, Wt, b_f, b_i, Pf, Pi);

    attn_mfma<<<dim3(BB * HC, 9), dim3(256), 0, stream>>>(
        Pf, Pi, maskp, flags, Osv, Osl);

    gemm_out_mfma<<<dim3(72, 6), dim3(256), 0, stream>>>(
        Osv, Osl, Wt, bu_v, bu_l, (float*)d_out);
}